// Round 2
// baseline (897.151 us; speedup 1.0000x reference)
//
#include <hip/hip_runtime.h>
#include <hip/hip_bf16.h>
#include <stdint.h>

#define DEVI __device__ __forceinline__

typedef __attribute__((ext_vector_type(8))) short bf16x8;   // 8 bf16 = 4 VGPRs
typedef __attribute__((ext_vector_type(4))) float f32x4;    // MFMA acc

static constexpr int Bb = 4, Ss = 8192, Ff = 1024, Hh = 16, Dd = 64;
static constexpr int Mm = Bb * Ss;                 // 32768 rows of the projection GEMMs
static constexpr int Kk = Ff;                      // 1024
static constexpr int PROJ_ELEMS = Mm * Ff;         // 33554432 per projection
static constexpr int NGROUP = PROJ_ELEMS / 64;     // 524288 LN groups per tensor

// ---------- small helpers ----------
DEVI ushort f2bf(float f) {            // fp32 -> bf16 RNE (manual, finite inputs)
  uint32_t u = __builtin_bit_cast(uint32_t, f);
  u += 0x7fffu + ((u >> 16) & 1u);
  return (ushort)(u >> 16);
}
DEVI float bf2f(ushort u) { return __builtin_bit_cast(float, (uint32_t)u << 16); }

DEVI uint32_t pack2(float a, float b) {  // 2×fp32 -> packed bf16x2 (manual RNE)
  return (uint32_t)f2bf(a) | ((uint32_t)f2bf(b) << 16);
}

DEVI void async16(void* lds, const void* g) {  // 16B/lane global->LDS DMA
  __builtin_amdgcn_global_load_lds((const __attribute__((address_space(1))) void*)g,
                                   (__attribute__((address_space(3))) void*)lds,
                                   16, 0, 0);
}

// ---------- kernel 1: W (K,N) fp32 -> Wt (N,K) bf16, so GEMM B-frags are K-contiguous ----------
__global__ __launch_bounds__(256) void wt_kernel(const float* __restrict__ Wq,
                                                 const float* __restrict__ Wk,
                                                 const float* __restrict__ Wv,
                                                 ushort* __restrict__ wt) {
  __shared__ float tile[64][65];
  int b = blockIdx.x;
  const int w = b >> 8; b &= 255;
  const int kt = b >> 4, nt = b & 15;         // 16x16 tiles of 64x64
  const float* Wsrc = (w == 0) ? Wq : ((w == 1) ? Wk : Wv);
  ushort* dst = wt + (size_t)w * 1024 * 1024;
  const int t = threadIdx.x;
  const int r = t >> 6, c = t & 63;
#pragma unroll
  for (int i = 0; i < 16; i++) {
    const int kk = kt * 64 + r + i * 4;
    tile[r + i * 4][c] = Wsrc[(size_t)kk * 1024 + nt * 64 + c];
  }
  __syncthreads();
#pragma unroll
  for (int i = 0; i < 16; i++) {
    const int nn = nt * 64 + r + i * 4;
    dst[(size_t)nn * 1024 + kt * 64 + c] = f2bf(tile[c][r + i * 4]);
  }
}

// ---------- kernel 2: QKV projection GEMM, m97 structure ----------
// C[proj] (32768x1024 bf16) = A[proj] (fp32, row-major MxK) * W (via Wt, NxK bf16)
// 128x128 tile, BK=64, 4 waves in 2x2, 16x16x32 bf16 MFMA, B via global_load_lds(16B).
__global__ __launch_bounds__(256, 3) void gemm_qkv_kernel(
    const float* __restrict__ Aq, const float* __restrict__ Ak,
    const float* __restrict__ Av, const ushort* __restrict__ Wt,
    ushort* __restrict__ Cout) {
  __shared__ __align__(16) ushort As[128][64];
  __shared__ __align__(16) ushort Bs[128][64];

  const int bx = blockIdx.x;
  const int proj = bx >> 11;
  const int t2 = bx & 2047;
  const int mt = t2 >> 3;       // 256 M-tiles
  const int nt = t2 & 7;        // 8 N-tiles (fastest -> same A strip in 8 consecutive blocks)
  const float* A = (proj == 0) ? Aq : ((proj == 1) ? Ak : Av);
  const ushort* Bw = Wt + (size_t)proj * 1024 * 1024;
  ushort* C = Cout + (size_t)proj * PROJ_ELEMS;
  const int m0 = mt * 128, n0 = nt * 128;
  const int tid = threadIdx.x;
  const int lane = tid & 63;
  const int wave = tid >> 6;
  const int wy = wave >> 1, wx = wave & 1;

  // A staging map: thread -> (row = tid>>3 + i*32, col = (tid&7)*8); LDS writes contiguous per wave
  const int ar = tid >> 3;
  const int ac = (tid & 7) * 8;
  const float* Abase = A + (size_t)m0 * Kk;

  const f32x4 fzero = {0.0f, 0.0f, 0.0f, 0.0f};
  f32x4 acc[4][4];
#pragma unroll
  for (int i = 0; i < 4; i++)
#pragma unroll
    for (int j = 0; j < 4; j++) acc[i][j] = fzero;

  for (int k0 = 0; k0 < Kk; k0 += 64) {
    // B: async DMA, 4 segs/wave, each seg = 8 rows x 64 cols bf16 = 1KB (lane l -> base + 16*l)
#pragma unroll
    for (int j = 0; j < 4; j++) {
      const int seg = wave * 4 + j;
      const int brow = seg * 8 + (lane >> 3);
      const int bcol = (lane & 7) * 8;
      async16(&Bs[seg * 8][0], Bw + (size_t)(n0 + brow) * Kk + k0 + bcol);
    }
    // A: fp32 loads + packed cvt + ds_write_b128
#pragma unroll
    for (int i = 0; i < 4; i++) {
      const int row = ar + i * 32;
      const float* src = Abase + (size_t)row * Kk + k0 + ac;
      const float4 f0 = *(const float4*)src;
      const float4 f1 = *(const float4*)(src + 4);
      uint4 v;
      v.x = pack2(f0.x, f0.y);
      v.y = pack2(f0.z, f0.w);
      v.z = pack2(f1.x, f1.y);
      v.w = pack2(f1.z, f1.w);
      *(uint4*)&As[row][ac] = v;
    }
    __syncthreads();
#pragma unroll
    for (int ks = 0; ks < 2; ks++) {
      bf16x8 af[4], bv[4];
#pragma unroll
      for (int i = 0; i < 4; i++)
        af[i] = *(const bf16x8*)&As[wy * 64 + i * 16 + (lane & 15)][ks * 32 + (lane >> 4) * 8];
#pragma unroll
      for (int j = 0; j < 4; j++)
        bv[j] = *(const bf16x8*)&Bs[wx * 64 + j * 16 + (lane & 15)][ks * 32 + (lane >> 4) * 8];
#pragma unroll
      for (int i = 0; i < 4; i++)
#pragma unroll
        for (int j = 0; j < 4; j++)
          acc[i][j] = __builtin_amdgcn_mfma_f32_16x16x32_bf16(af[i], bv[j], acc[i][j], 0, 0, 0);
    }
    __syncthreads();
  }
  // epilogue: C/D layout col=lane&15, row=(lane>>4)*4+reg
#pragma unroll
  for (int i = 0; i < 4; i++) {
    const int rbase = m0 + wy * 64 + i * 16 + (lane >> 4) * 4;
#pragma unroll
    for (int j = 0; j < 4; j++) {
      const int col = n0 + wx * 64 + j * 16 + (lane & 15);
#pragma unroll
      for (int r = 0; r < 4; r++)
        C[(size_t)(rbase + r) * 1024 + col] = f2bf(acc[i][j][r]);
    }
  }
}

// ---------- kernel 3: in-place per-head LayerNorm on K and V (bf16) ----------
// group = 64 contiguous elems; h = (group>>13)&15 ; 8 groups per wave pass, 16B/lane
__global__ __launch_bounds__(256) void ln_kernel(
    ushort* __restrict__ kp, ushort* __restrict__ vp,
    const float* __restrict__ ksc, const float* __restrict__ kbi,
    const float* __restrict__ vsc, const float* __restrict__ vbi) {
  const int lane = threadIdx.x & 63;
  const int gwave = (blockIdx.x * 256 + threadIdx.x) >> 6;
  const int nw = (gridDim.x * 256) >> 6;
  const int sub = lane >> 3;           // which of 8 groups in this wave
  const int off = (lane & 7) * 8;      // element offset within group
  const int npass = NGROUP / 8;        // 65536
  for (int p = gwave; p < npass; p += nw) {
    const size_t g = (size_t)p * 8 + sub;
    const int h = (int)((g >> 13) & 15);
    const size_t base = g * 64 + off;
#pragma unroll
    for (int which = 0; which < 2; which++) {
      ushort* ptr = which ? vp : kp;
      const float* sc = which ? vsc : ksc;
      const float* bi = which ? vbi : kbi;
      const uint4 raw = *(const uint4*)(ptr + base);
      const uint32_t* rw = (const uint32_t*)&raw;
      float x[8];
#pragma unroll
      for (int j = 0; j < 4; j++) {
        x[2 * j] = bf2f((ushort)(rw[j] & 0xffffu));
        x[2 * j + 1] = bf2f((ushort)(rw[j] >> 16));
      }
      float s = 0.f, sq = 0.f;
#pragma unroll
      for (int j = 0; j < 8; j++) { s += x[j]; sq += x[j] * x[j]; }
      s += __shfl_xor(s, 1); s += __shfl_xor(s, 2); s += __shfl_xor(s, 4);
      sq += __shfl_xor(sq, 1); sq += __shfl_xor(sq, 2); sq += __shfl_xor(sq, 4);
      const float mean = s * (1.0f / 64.0f);
      const float var = sq * (1.0f / 64.0f) - mean * mean;
      const float rs = rsqrtf(var + 1e-6f);
      uint4 outv;
      uint32_t* ow = (uint32_t*)&outv;
#pragma unroll
      for (int j = 0; j < 4; j++) {
        const int d0 = off + 2 * j;
        const float y0 = (x[2 * j] - mean) * rs * sc[h * 64 + d0] + bi[h * 64 + d0];
        const float y1 = (x[2 * j + 1] - mean) * rs * sc[h * 64 + d0 + 1] + bi[h * 64 + d0 + 1];
        ow[j] = pack2(y0, y1);
      }
      *(uint4*)(ptr + base) = outv;
    }
  }
}

// ---------- kernel 4: p_raw += K^T V partials (split-K over 8 chunks of 1024 rows) ----------
__global__ __launch_bounds__(256) void pattn_kernel(const ushort* __restrict__ kp,
                                                    const ushort* __restrict__ vp,
                                                    float* __restrict__ praw) {
  __shared__ __align__(16) ushort kT[64][72];   // (d, n) transposed, pad 72 breaks bank stride
  __shared__ __align__(16) ushort vT[64][72];   // (e, n)
  const int bh = blockIdx.x >> 3;
  const int nc = blockIdx.x & 7;
  const ushort* kb = kp + ((size_t)bh << 19) + (size_t)nc * 65536;
  const ushort* vb = vp + ((size_t)bh << 19) + (size_t)nc * 65536;
  const int tid = threadIdx.x;
  const int lane = tid & 63;
  const int wave = tid >> 6;
  const int d0 = wave * 16;
  const f32x4 fzero = {0.0f, 0.0f, 0.0f, 0.0f};
  f32x4 acc[4];
#pragma unroll
  for (int e = 0; e < 4; e++) acc[e] = fzero;

  for (int c = 0; c < 16; c++) {   // 16 sub-chunks of 64 n-rows
    const ushort* kc = kb + c * 4096;
    const ushort* vc = vb + c * 4096;
    // lane = n index; wave covers d0..d0+15
    const uint4 ka = *(const uint4*)(kc + (size_t)lane * 64 + d0);
    const uint4 ka2 = *(const uint4*)(kc + (size_t)lane * 64 + d0 + 8);
    const uint4 va = *(const uint4*)(vc + (size_t)lane * 64 + d0);
    const uint4 va2 = *(const uint4*)(vc + (size_t)lane * 64 + d0 + 8);
    __syncthreads();   // previous compute done before overwriting LDS
    const uint32_t* kw = (const uint32_t*)&ka;
    const uint32_t* kw2 = (const uint32_t*)&ka2;
    const uint32_t* vw = (const uint32_t*)&va;
    const uint32_t* vw2 = (const uint32_t*)&va2;
#pragma unroll
    for (int j = 0; j < 4; j++) {   // all lanes same d -> contiguous 2B writes, conflict-free
      kT[d0 + 2 * j][lane] = (ushort)(kw[j] & 0xffffu);
      kT[d0 + 2 * j + 1][lane] = (ushort)(kw[j] >> 16);
      kT[d0 + 8 + 2 * j][lane] = (ushort)(kw2[j] & 0xffffu);
      kT[d0 + 8 + 2 * j + 1][lane] = (ushort)(kw2[j] >> 16);
      vT[d0 + 2 * j][lane] = (ushort)(vw[j] & 0xffffu);
      vT[d0 + 2 * j + 1][lane] = (ushort)(vw[j] >> 16);
      vT[d0 + 8 + 2 * j][lane] = (ushort)(vw2[j] & 0xffffu);
      vT[d0 + 8 + 2 * j + 1][lane] = (ushort)(vw2[j] >> 16);
    }
    __syncthreads();
#pragma unroll
    for (int ks = 0; ks < 2; ks++) {
      const bf16x8 af = *(const bf16x8*)&kT[wave * 16 + (lane & 15)][ks * 32 + (lane >> 4) * 8];
#pragma unroll
      for (int e = 0; e < 4; e++) {
        const bf16x8 bv = *(const bf16x8*)&vT[e * 16 + (lane & 15)][ks * 32 + (lane >> 4) * 8];
        acc[e] = __builtin_amdgcn_mfma_f32_16x16x32_bf16(af, bv, acc[e], 0, 0, 0);
      }
    }
  }
#pragma unroll
  for (int e = 0; e < 4; e++)
#pragma unroll
    for (int r = 0; r < 4; r++) {
      const int drow = wave * 16 + (lane >> 4) * 4 + r;
      const int ecol = e * 16 + (lane & 15);
      atomicAdd(&praw[(size_t)bh * 4096 + drow * 64 + ecol], acc[e][r]);
    }
}

// ---------- kernel 5: p_out = p_raw / 8192 ----------
__global__ __launch_bounds__(256) void scalep_kernel(const float* __restrict__ praw,
                                                     float* __restrict__ pout) {
  const int i = blockIdx.x * 256 + threadIdx.x;
  pout[i] = praw[i] * (1.0f / 8192.0f);
}

// ---------- kernel 6: att = Q * (p_raw/8192) per (b,h); A-frags straight from global ----------
__global__ __launch_bounds__(256) void outgemm_kernel(const ushort* __restrict__ qp,
                                                      const float* __restrict__ praw,
                                                      float* __restrict__ xout) {
  __shared__ __align__(16) ushort pT[64][72];   // (e, d) so B-frags are d-contiguous
  const int bh = blockIdx.x >> 4;
  const int mc = blockIdx.x & 15;               // 16 chunks of 512 rows
  const ushort* qb = qp + ((size_t)bh << 19) + (size_t)mc * 512 * 64;
  float* ob = xout + ((size_t)bh << 19) + (size_t)mc * 512 * 64;
  const float* pb = praw + (size_t)bh * 4096;
  const int tid = threadIdx.x;
  const int lane = tid & 63;
  const int wave = tid >> 6;
  for (int i = tid; i < 4096; i += 256) {
    const int d = i >> 6, e = i & 63;
    pT[e][d] = f2bf(pb[i] * (1.0f / 8192.0f));
  }
  __syncthreads();
  bf16x8 bv[4][2];
#pragma unroll
  for (int e = 0; e < 4; e++)
#pragma unroll
    for (int ks = 0; ks < 2; ks++)
      bv[e][ks] = *(const bf16x8*)&pT[e * 16 + (lane & 15)][ks * 32 + (lane >> 4) * 8];
  const f32x4 fzero = {0.0f, 0.0f, 0.0f, 0.0f};
  for (int it = 0; it < 8; it++) {
    const int rbase = it * 64 + wave * 16;
    const ushort* qrow = qb + (size_t)rbase * 64;
    const bf16x8 a0 = *(const bf16x8*)(qrow + (size_t)(lane & 15) * 64 + (lane >> 4) * 8);
    const bf16x8 a1 = *(const bf16x8*)(qrow + (size_t)(lane & 15) * 64 + (lane >> 4) * 8 + 32);
    f32x4 acc[4];
#pragma unroll
    for (int e = 0; e < 4; e++) acc[e] = fzero;
#pragma unroll
    for (int e = 0; e < 4; e++) {
      acc[e] = __builtin_amdgcn_mfma_f32_16x16x32_bf16(a0, bv[e][0], acc[e], 0, 0, 0);
      acc[e] = __builtin_amdgcn_mfma_f32_16x16x32_bf16(a1, bv[e][1], acc[e], 0, 0, 0);
    }
#pragma unroll
    for (int e = 0; e < 4; e++)
#pragma unroll
      for (int r = 0; r < 4; r++)
        ob[(size_t)(rbase + (lane >> 4) * 4 + r) * 64 + e * 16 + (lane & 15)] = acc[e][r];
  }
}

extern "C" void kernel_launch(void* const* d_in, const int* in_sizes, int n_in,
                              void* d_out, int out_size, void* d_ws, size_t ws_size,
                              hipStream_t stream) {
  const float* q_in = (const float*)d_in[0];
  const float* k_in = (const float*)d_in[1];
  const float* v_in = (const float*)d_in[2];
  const float* Wq = (const float*)d_in[3];
  const float* Wk = (const float*)d_in[4];
  const float* Wv = (const float*)d_in[5];
  const float* ksc = (const float*)d_in[6];
  const float* kbi = (const float*)d_in[7];
  const float* vsc = (const float*)d_in[8];
  const float* vbi = (const float*)d_in[9];

  // ws layout: q/k/v projections bf16 (3x64MB) | Wt bf16 (3x2MB) | p_raw fp32 (1MB)
  ushort* q_proj = (ushort*)d_ws;
  ushort* k_proj = q_proj + (size_t)PROJ_ELEMS;
  ushort* v_proj = k_proj + (size_t)PROJ_ELEMS;
  ushort* wtb = v_proj + (size_t)PROJ_ELEMS;
  float* praw = (float*)(wtb + (size_t)3 * 1024 * 1024);

  float* att = (float*)d_out;                    // 33554432 fp32
  float* pout = att + (size_t)PROJ_ELEMS;        // 262144 fp32

  wt_kernel<<<768, 256, 0, stream>>>(Wq, Wk, Wv, wtb);
  gemm_qkv_kernel<<<6144, 256, 0, stream>>>(q_in, k_in, v_in, wtb, q_proj);
  ln_kernel<<<1024, 256, 0, stream>>>(k_proj, v_proj, ksc, kbi, vsc, vbi);
  (void)hipMemsetAsync(praw, 0, (size_t)Bb * Hh * 64 * 64 * sizeof(float), stream);
  pattn_kernel<<<512, 256, 0, stream>>>(k_proj, v_proj, praw);
  scalep_kernel<<<1024, 256, 0, stream>>>(praw, pout);
  outgemm_kernel<<<1024, 256, 0, stream>>>(q_proj, praw, att);
}